// Round 1
// baseline (808.095 us; speedup 1.0000x reference)
//
#include <hip/hip_runtime.h>
#include <stdint.h>

#define NN 25000
#define NE 400000
#define DD 1024

typedef __attribute__((ext_vector_type(8))) short short8;
typedef __attribute__((ext_vector_type(4))) float f32x4;

__device__ __forceinline__ unsigned short f2bf(float f) {
  union { float f; uint32_t u; } v; v.f = f;
  uint32_t r = v.u + 0x7fffu + ((v.u >> 16) & 1u);
  return (unsigned short)(r >> 16);
}
__device__ __forceinline__ float bf2f(unsigned short h) {
  union { uint32_t u; float f; } v; v.u = ((uint32_t)h) << 16;
  return v.f;
}

__device__ __forceinline__ void gld_lds16(const void* g, void* l) {
  __builtin_amdgcn_global_load_lds(
      (const __attribute__((address_space(1))) void*)g,
      (__attribute__((address_space(3))) void*)l, 16, 0, 0);
}

// ---------------- cast fp32 -> bf16 (vectorized) ----------------
__global__ __launch_bounds__(256) void k_cast_bf16(const float* __restrict__ in,
                                                   unsigned short* __restrict__ out,
                                                   int n8) {
  int i = blockIdx.x * blockDim.x + threadIdx.x;
  int stride = gridDim.x * blockDim.x;
  for (; i < n8; i += stride) {
    const float4* p = (const float4*)(in + (size_t)i * 8);
    float4 a = p[0], b = p[1];
    ushort4 r0, r1;
    r0.x = f2bf(a.x); r0.y = f2bf(a.y); r0.z = f2bf(a.z); r0.w = f2bf(a.w);
    r1.x = f2bf(b.x); r1.y = f2bf(b.y); r1.z = f2bf(b.z); r1.w = f2bf(b.w);
    ushort4* q = (ushort4*)(out + (size_t)i * 8);
    q[0] = r0; q[1] = r1;
  }
}

// ------------- transpose+cast W[k][n] fp32 -> WT[n][2048] bf16 at col kofs -------------
__global__ __launch_bounds__(256) void k_transcast(const float* __restrict__ W,
                                                   unsigned short* __restrict__ WT,
                                                   int kofs) {
  __shared__ unsigned short tile[64][66];  // +2 pad: conflict-free transpose read
  int t = threadIdx.x;
  int k0 = blockIdx.x * 64, n0 = blockIdx.y * 64;
#pragma unroll
  for (int p = 0; p < 16; ++p) {
    int idx = p * 256 + t;
    int lr = idx >> 6, lc = idx & 63;
    tile[lr][lc] = f2bf(W[(size_t)(k0 + lr) * 1024 + n0 + lc]);
  }
  __syncthreads();
#pragma unroll
  for (int p = 0; p < 16; ++p) {
    int idx = p * 256 + t;
    int lr = idx >> 6, lc = idx & 63;  // lr = local n, lc = local k
    WT[(size_t)(n0 + lr) * 2048 + kofs + k0 + lc] = tile[lc][lr];
  }
}

// ---------------- degree ----------------
__global__ __launch_bounds__(256) void k_deg(const int* __restrict__ dst,
                                             int* __restrict__ deg, int E) {
  int i = blockIdx.x * blockDim.x + threadIdx.x;
  if (i < E) atomicAdd(&deg[dst[i]], 1);
}

// ---------------- exclusive scan (single block, 1024 thr) ----------------
__global__ __launch_bounds__(1024) void k_scan(const int* __restrict__ deg,
                                               int* __restrict__ rowptr,
                                               int* __restrict__ cursor,
                                               float* __restrict__ deg_inv, int N) {
  __shared__ int wsum[16];
  __shared__ int carry_s;
  int t = threadIdx.x, lane = t & 63, w = t >> 6;
  if (t == 0) carry_s = 0;
  __syncthreads();
  for (int base = 0; base < N; base += 1024) {
    int i = base + t;
    int v = (i < N) ? deg[i] : 0;
    int x = v;
#pragma unroll
    for (int off = 1; off < 64; off <<= 1) {
      int y = __shfl_up(x, off);
      if (lane >= off) x += y;
    }
    __syncthreads();  // protect wsum/carry_s from previous iteration
    if (lane == 63) wsum[w] = x;
    __syncthreads();
    if (w == 0 && lane < 16) {
      int s = wsum[lane];
#pragma unroll
      for (int off = 1; off < 16; off <<= 1) {
        int y = __shfl_up(s, off);
        if (lane >= off) s += y;
      }
      wsum[lane] = s;
    }
    __syncthreads();
    int wbase = (w > 0) ? wsum[w - 1] : 0;
    int incl = wbase + x;
    int carry = carry_s;
    if (i < N) {
      int excl = carry + incl - v;
      rowptr[i] = excl;
      cursor[i] = excl;
      deg_inv[i] = 1.0f / fmaxf((float)v, 1.0f);
    }
    __syncthreads();  // everyone has read carry_s/wsum
    if (t == 1023) carry_s = carry + incl;
  }
  __syncthreads();
  if (t == 0) rowptr[N] = carry_s;
}

// ---------------- CSR fill (counting sort) ----------------
__global__ __launch_bounds__(256) void k_fill(const int* __restrict__ src,
                                              const int* __restrict__ dst,
                                              int* __restrict__ cursor,
                                              int* __restrict__ srcs, int E) {
  int i = blockIdx.x * blockDim.x + threadIdx.x;
  if (i < E) {
    int p = atomicAdd(&cursor[dst[i]], 1);
    srcs[p] = src[i];
  }
}

// ---------------- mean aggregation: one block per dst node ----------------
__global__ __launch_bounds__(256) void k_agg(const unsigned short* __restrict__ h,
                                             const int* __restrict__ rowptr,
                                             const int* __restrict__ srcs,
                                             const float* __restrict__ deg_inv,
                                             unsigned short* __restrict__ mean) {
  int node = blockIdx.x;
  int t = threadIdx.x;
  int beg = rowptr[node], end = rowptr[node + 1];
  int c = t * 4;  // 4 columns per thread
  float a0 = 0.f, a1 = 0.f, a2 = 0.f, a3 = 0.f;
  int e = beg;
  for (; e + 1 < end; e += 2) {  // unroll x2 for memory ILP
    int s0 = srcs[e], s1 = srcs[e + 1];
    ushort4 v0 = *(const ushort4*)(h + (size_t)s0 * DD + c);
    ushort4 v1 = *(const ushort4*)(h + (size_t)s1 * DD + c);
    a0 += bf2f(v0.x) + bf2f(v1.x);
    a1 += bf2f(v0.y) + bf2f(v1.y);
    a2 += bf2f(v0.z) + bf2f(v1.z);
    a3 += bf2f(v0.w) + bf2f(v1.w);
  }
  if (e < end) {
    int s0 = srcs[e];
    ushort4 v0 = *(const ushort4*)(h + (size_t)s0 * DD + c);
    a0 += bf2f(v0.x); a1 += bf2f(v0.y); a2 += bf2f(v0.z); a3 += bf2f(v0.w);
  }
  float di = deg_inv[node];
  ushort4 r;
  r.x = f2bf(a0 * di); r.y = f2bf(a1 * di); r.z = f2bf(a2 * di); r.w = f2bf(a3 * di);
  *(ushort4*)(mean + (size_t)node * DD + c) = r;
}

// ---------------- fused dual-A GEMM: C = A1@Wself + A2@Wneigh + b ----------------
// A1,A2: [M][1024] bf16 row-major.  WT: [1024 n][2048 k] bf16 (pre-transposed, k<1024
// from W_self, k>=1024 from W_neigh).  128x128 tile, BK=32, 4 waves (2x2 of 64x64),
// mfma_f32_16x16x32_bf16, global_load_lds width-16 staging (m97 structure).
template <bool RELU, bool OUT_BF16>
__global__ __launch_bounds__(256) void k_gemm(const unsigned short* __restrict__ A1,
                                              const unsigned short* __restrict__ A2,
                                              const unsigned short* __restrict__ WT,
                                              const float* __restrict__ bias,
                                              void* __restrict__ Cout, int M) {
  __shared__ __align__(16) unsigned short lA[128 * 32];  // 8 KB, [row][32k] linear
  __shared__ __align__(16) unsigned short lB[128 * 32];  // 8 KB
  const int t = threadIdx.x;
  const int lane = t & 63, wave = t >> 6;
  const int wm = wave >> 1, wn = wave & 1;        // 2x2 wave grid
  const int bn = blockIdx.x, bm = blockIdx.y;     // bn fastest: 8 blocks share A panel
  const int fr = lane & 15, fq = lane >> 4;

  f32x4 acc[4][4];
#pragma unroll
  for (int m = 0; m < 4; ++m)
#pragma unroll
    for (int n = 0; n < 4; ++n) acc[m][n] = (f32x4){0.f, 0.f, 0.f, 0.f};

  // staging geometry: thread t covers tile bytes [t*16, t*16+16) per 4KB chunk
  const int srow = t >> 2;          // 0..63 (chunk-local row)
  const int skk = (t & 3) * 8;      // k-element offset within row
  int ar0 = bm * 128 + srow;
  int ar1 = ar0 + 64;
  if (ar0 > M - 1) ar0 = M - 1;     // clamp tail-tile reads (stores are guarded)
  if (ar1 > M - 1) ar1 = M - 1;
  const int br0 = bn * 128 + srow;
  const int br1 = br0 + 64;
  unsigned short* ldsA0 = lA + wave * 512;        // wave-uniform LDS dest bases
  unsigned short* ldsA1 = lA + 2048 + wave * 512;
  unsigned short* ldsB0 = lB + wave * 512;
  unsigned short* ldsB1 = lB + 2048 + wave * 512;

  for (int kt = 0; kt < 64; ++kt) {
    const unsigned short* As = (kt < 32) ? A1 : A2;
    const int ka = (kt & 31) * 32 + skk;  // k within A matrix [0,1024)
    const int kw = kt * 32 + skk;         // k within WT       [0,2048)
    __syncthreads();  // previous iteration's ds_reads done before overwrite
    gld_lds16(As + (size_t)ar0 * 1024 + ka, ldsA0);
    gld_lds16(As + (size_t)ar1 * 1024 + ka, ldsA1);
    gld_lds16(WT + (size_t)br0 * 2048 + kw, ldsB0);
    gld_lds16(WT + (size_t)br1 * 2048 + kw, ldsB1);
    __syncthreads();  // compiler drains vmcnt before s_barrier -> tiles ready

    short8 af[4], bfr[4];
#pragma unroll
    for (int m = 0; m < 4; ++m)
      af[m] = *(const short8*)&lA[(wm * 64 + m * 16 + fr) * 32 + fq * 8];
#pragma unroll
    for (int n = 0; n < 4; ++n)
      bfr[n] = *(const short8*)&lB[(wn * 64 + n * 16 + fr) * 32 + fq * 8];
#pragma unroll
    for (int m = 0; m < 4; ++m)
#pragma unroll
      for (int n = 0; n < 4; ++n)
        acc[m][n] = __builtin_amdgcn_mfma_f32_16x16x32_bf16(af[m], bfr[n], acc[m][n], 0, 0, 0);
  }

  // epilogue: C/D layout col=lane&15, row=(lane>>4)*4+j  [m89/m91 verified]
#pragma unroll
  for (int m = 0; m < 4; ++m) {
    int r0 = bm * 128 + wm * 64 + m * 16 + fq * 4;
#pragma unroll
    for (int j = 0; j < 4; ++j) {
      int r = r0 + j;
      if (r >= M) continue;
#pragma unroll
      for (int n = 0; n < 4; ++n) {
        int cc = bn * 128 + wn * 64 + n * 16 + fr;
        float v = acc[m][n][j] + bias[cc];
        if (RELU) v = fmaxf(v, 0.f);
        if (OUT_BF16)
          ((unsigned short*)Cout)[(size_t)r * 1024 + cc] = f2bf(v);
        else
          ((float*)Cout)[(size_t)r * 1024 + cc] = v;
      }
    }
  }
}

extern "C" void kernel_launch(void* const* d_in, const int* in_sizes, int n_in,
                              void* d_out, int out_size, void* d_ws, size_t ws_size,
                              hipStream_t stream) {
  const float* x = (const float*)d_in[0];
  const int* esrc = (const int*)d_in[1];
  const int* edst = (const int*)d_in[2];
  const float* Ws0 = (const float*)d_in[3];
  const float* Wn0 = (const float*)d_in[4];
  const float* b0 = (const float*)d_in[5];
  const float* Ws1 = (const float*)d_in[6];
  const float* Wn1 = (const float*)d_in[7];
  const float* b1 = (const float*)d_in[8];
  float* out = (float*)d_out;

  // workspace carve-up (~165 MB)
  char* ws = (char*)d_ws;
  size_t off = 0;
  auto alloc = [&](size_t bytes) -> void* {
    void* p = ws + off;
    off = (off + bytes + 255) & ~(size_t)255;
    return p;
  };
  unsigned short* x_bf = (unsigned short*)alloc((size_t)NN * DD * 2);
  unsigned short* h_bf = (unsigned short*)alloc((size_t)NN * DD * 2);
  unsigned short* mean_bf = (unsigned short*)alloc((size_t)NN * DD * 2);
  unsigned short* WT0 = (unsigned short*)alloc((size_t)DD * 2048 * 2);
  unsigned short* WT1 = (unsigned short*)alloc((size_t)DD * 2048 * 2);
  int* deg = (int*)alloc((size_t)NN * 4);
  int* rowptr = (int*)alloc((size_t)(NN + 1) * 4);
  int* cursor = (int*)alloc((size_t)NN * 4);
  float* dinv = (float*)alloc((size_t)NN * 4);
  int* srcs = (int*)alloc((size_t)NE * 4);

  hipMemsetAsync(deg, 0, (size_t)NN * 4, stream);

  k_cast_bf16<<<2048, 256, 0, stream>>>(x, x_bf, NN * DD / 8);
  dim3 tg(16, 16);
  k_transcast<<<tg, 256, 0, stream>>>(Ws0, WT0, 0);
  k_transcast<<<tg, 256, 0, stream>>>(Wn0, WT0, 1024);
  k_transcast<<<tg, 256, 0, stream>>>(Ws1, WT1, 0);
  k_transcast<<<tg, 256, 0, stream>>>(Wn1, WT1, 1024);

  k_deg<<<(NE + 255) / 256, 256, 0, stream>>>(edst, deg, NE);
  k_scan<<<1, 1024, 0, stream>>>(deg, rowptr, cursor, dinv, NN);
  k_fill<<<(NE + 255) / 256, 256, 0, stream>>>(esrc, edst, cursor, srcs, NE);

  dim3 gg(8, (NN + 127) / 128);  // bn fastest -> consecutive blocks share A panel

  // layer 0
  k_agg<<<NN, 256, 0, stream>>>(x_bf, rowptr, srcs, dinv, mean_bf);
  k_gemm<true, true><<<gg, 256, 0, stream>>>(x_bf, mean_bf, WT0, b0, (void*)h_bf, NN);

  // layer 1
  k_agg<<<NN, 256, 0, stream>>>(h_bf, rowptr, srcs, dinv, mean_bf);
  k_gemm<false, false><<<gg, 256, 0, stream>>>(h_bf, mean_bf, WT1, b1, (void*)out, NN);
}

// Round 3
// 786.722 us; speedup vs baseline: 1.0272x; 1.0272x over previous
//
#include <hip/hip_runtime.h>
#include <stdint.h>

#define NN 25000
#define NE 400000
#define DD 1024

typedef __attribute__((ext_vector_type(8))) short short8;
typedef __attribute__((ext_vector_type(4))) float f32x4;

__device__ __forceinline__ unsigned short f2bf(float f) {
  union { float f; uint32_t u; } v; v.f = f;
  uint32_t r = v.u + 0x7fffu + ((v.u >> 16) & 1u);
  return (unsigned short)(r >> 16);
}
__device__ __forceinline__ float bf2f(unsigned short h) {
  union { uint32_t u; float f; } v; v.u = ((uint32_t)h) << 16;
  return v.f;
}

__device__ __forceinline__ void gld_lds16(const void* g, void* l) {
  __builtin_amdgcn_global_load_lds(
      (const __attribute__((address_space(1))) void*)g,
      (__attribute__((address_space(3))) void*)l, 16, 0, 0);
}

// ---------------- cast fp32 -> bf16 (vectorized) ----------------
__global__ __launch_bounds__(256) void k_cast_bf16(const float* __restrict__ in,
                                                   unsigned short* __restrict__ out,
                                                   int n8) {
  int i = blockIdx.x * blockDim.x + threadIdx.x;
  int stride = gridDim.x * blockDim.x;
  for (; i < n8; i += stride) {
    const float4* p = (const float4*)(in + (size_t)i * 8);
    float4 a = p[0], b = p[1];
    ushort4 r0, r1;
    r0.x = f2bf(a.x); r0.y = f2bf(a.y); r0.z = f2bf(a.z); r0.w = f2bf(a.w);
    r1.x = f2bf(b.x); r1.y = f2bf(b.y); r1.z = f2bf(b.z); r1.w = f2bf(b.w);
    ushort4* q = (ushort4*)(out + (size_t)i * 8);
    q[0] = r0; q[1] = r1;
  }
}

// ------------- transpose+cast W[k][n] fp32 -> WT[n][2048] bf16 at col kofs -------------
__global__ __launch_bounds__(256) void k_transcast(const float* __restrict__ W,
                                                   unsigned short* __restrict__ WT,
                                                   int kofs) {
  __shared__ unsigned short tile[64][66];  // +2 pad: conflict-free transpose read
  int t = threadIdx.x;
  int k0 = blockIdx.x * 64, n0 = blockIdx.y * 64;
#pragma unroll
  for (int p = 0; p < 16; ++p) {
    int idx = p * 256 + t;
    int lr = idx >> 6, lc = idx & 63;
    tile[lr][lc] = f2bf(W[(size_t)(k0 + lr) * 1024 + n0 + lc]);
  }
  __syncthreads();
#pragma unroll
  for (int p = 0; p < 16; ++p) {
    int idx = p * 256 + t;
    int lr = idx >> 6, lc = idx & 63;  // lr = local n, lc = local k
    WT[(size_t)(n0 + lr) * 2048 + kofs + k0 + lc] = tile[lc][lr];
  }
}

// ---------------- degree ----------------
__global__ __launch_bounds__(256) void k_deg(const int* __restrict__ dst,
                                             int* __restrict__ deg, int E) {
  int i = blockIdx.x * blockDim.x + threadIdx.x;
  if (i < E) atomicAdd(&deg[dst[i]], 1);
}

// ---------------- two-level exclusive scan ----------------
// pass 1: per-block (256 elems) local exclusive scan + block sums
__global__ __launch_bounds__(256) void k_scan1(const int* __restrict__ deg,
                                               int* __restrict__ rowptr,
                                               int* __restrict__ bsum, int N) {
  __shared__ int ws[4];
  int t = threadIdx.x, lane = t & 63, w = t >> 6;
  int i = blockIdx.x * 256 + t;
  int v = (i < N) ? deg[i] : 0;
  int x = v;
#pragma unroll
  for (int off = 1; off < 64; off <<= 1) {
    int y = __shfl_up(x, off);
    if (lane >= off) x += y;
  }
  if (lane == 63) ws[w] = x;
  __syncthreads();
  int wbase = 0;
#pragma unroll
  for (int j = 0; j < 3; ++j)
    if (w > j) wbase += ws[j];
  if (i < N) rowptr[i] = wbase + x - v;  // local exclusive
  if (t == 255) bsum[blockIdx.x] = wbase + x;
}

// pass 2: scan the (<=128) block sums; write grand total to rowptr[N]
__global__ __launch_bounds__(128) void k_scan2(const int* __restrict__ bsum,
                                               int* __restrict__ boff,
                                               int* __restrict__ rowptr_end, int nb) {
  __shared__ int ws[2];
  int t = threadIdx.x, lane = t & 63, w = t >> 6;
  int v = (t < nb) ? bsum[t] : 0;
  int x = v;
#pragma unroll
  for (int off = 1; off < 64; off <<= 1) {
    int y = __shfl_up(x, off);
    if (lane >= off) x += y;
  }
  if (lane == 63) ws[w] = x;
  __syncthreads();
  int wbase = (w == 1) ? ws[0] : 0;
  if (t < nb) boff[t] = wbase + x - v;
  if (t == 127) *rowptr_end = wbase + x;
}

// pass 3: add block offsets, init cursor and deg_inv
__global__ __launch_bounds__(256) void k_scan3(const int* __restrict__ deg,
                                               const int* __restrict__ boff,
                                               int* __restrict__ rowptr,
                                               int* __restrict__ cursor,
                                               float* __restrict__ dinv, int N) {
  int i = blockIdx.x * 256 + threadIdx.x;
  if (i < N) {
    int r = rowptr[i] + boff[blockIdx.x];
    rowptr[i] = r;
    cursor[i] = r;
    dinv[i] = 1.0f / fmaxf((float)deg[i], 1.0f);
  }
}

// ---------------- CSR fill (counting sort) ----------------
__global__ __launch_bounds__(256) void k_fill(const int* __restrict__ src,
                                              const int* __restrict__ dst,
                                              int* __restrict__ cursor,
                                              int* __restrict__ srcs, int E) {
  int i = blockIdx.x * blockDim.x + threadIdx.x;
  if (i < E) {
    int p = atomicAdd(&cursor[dst[i]], 1);
    srcs[p] = src[i];
  }
}

// ---------------- mean aggregation: 2 nodes per block, 16B/lane loads ----------------
__global__ __launch_bounds__(256) void k_agg(const unsigned short* __restrict__ h,
                                             const int* __restrict__ rowptr,
                                             const int* __restrict__ srcs,
                                             const float* __restrict__ deg_inv,
                                             unsigned short* __restrict__ mean, int N) {
  int node = blockIdx.x * 2 + (threadIdx.x >> 7);
  if (node >= N) return;
  int t = threadIdx.x & 127;
  int c = t * 8;  // 8 bf16 columns = 16 B per lane
  int beg = rowptr[node], end = rowptr[node + 1];
  float a[8];
#pragma unroll
  for (int j = 0; j < 8; ++j) a[j] = 0.f;
  int e = beg;
  for (; e + 1 < end; e += 2) {  // 2-deep for memory ILP
    int s0 = srcs[e], s1 = srcs[e + 1];
    short8 v0 = *(const short8*)(h + (size_t)s0 * DD + c);
    short8 v1 = *(const short8*)(h + (size_t)s1 * DD + c);
#pragma unroll
    for (int j = 0; j < 8; ++j)
      a[j] += bf2f((unsigned short)v0[j]) + bf2f((unsigned short)v1[j]);
  }
  if (e < end) {
    int s0 = srcs[e];
    short8 v0 = *(const short8*)(h + (size_t)s0 * DD + c);
#pragma unroll
    for (int j = 0; j < 8; ++j) a[j] += bf2f((unsigned short)v0[j]);
  }
  float di = deg_inv[node];
  short8 r;
#pragma unroll
  for (int j = 0; j < 8; ++j) r[j] = (short)f2bf(a[j] * di);
  *(short8*)(mean + (size_t)node * DD + c) = r;
}

// ---------------- fused dual-A GEMM: C = A1@Wself + A2@Wneigh + b ----------------
// A1,A2: [M][1024] bf16 row-major.  WT: [1024 n][2048 k] bf16 (k<1024 Wself, k>=1024
// Wneigh).  128x128 tile, BK=32, 4 waves (2x2 of 64x64), mfma_f32_16x16x32_bf16.
// Double-buffered LDS, 2-phase prefetch (stage next || compute cur, 1 barrier/K-step).
// XCD-contiguous tile swizzle: each XCD owns a contiguous bm-range (bn fastest) so the
// 8 blocks sharing an A panel land in ONE L2.
template <bool RELU, bool OUT_BF16>
__global__ __launch_bounds__(256) void k_gemm(const unsigned short* __restrict__ A1,
                                              const unsigned short* __restrict__ A2,
                                              const unsigned short* __restrict__ WT,
                                              const float* __restrict__ bias,
                                              void* __restrict__ Cout, int M) {
  __shared__ __align__(16) unsigned short lA[2][128 * 32];  // 2 x 8 KB
  __shared__ __align__(16) unsigned short lB[2][128 * 32];
  const int t = threadIdx.x;
  const int lane = t & 63, wave = t >> 6;
  const int wm = wave >> 1, wn = wave & 1;
  const int fr = lane & 15, fq = lane >> 4;

  // XCD swizzle: hw%8 = XCD (round-robin dispatch); give each XCD a contiguous
  // run of nbm tiles, bn-fastest (8 bn-blocks of one bm land on one XCD).
  const int nbm = gridDim.x >> 3;  // tiles per XCD (grid = 8 * nbm)
  const int hw = blockIdx.x;
  const int g = (hw & 7) * nbm + (hw >> 3);
  const int bm = g >> 3, bn = g & 7;

  f32x4 acc[4][4];
#pragma unroll
  for (int m = 0; m < 4; ++m)
#pragma unroll
    for (int n = 0; n < 4; ++n) acc[m][n] = (f32x4){0.f, 0.f, 0.f, 0.f};

  // staging geometry: thread t covers 16 bytes of a 4 KB chunk (64 rows x 64 B)
  const int srow = t >> 2;
  const int skk = (t & 3) * 8;
  int ar0 = bm * 128 + srow;
  int ar1 = ar0 + 64;
  if (ar0 > M - 1) ar0 = M - 1;  // clamp tail reads (stores guarded)
  if (ar1 > M - 1) ar1 = M - 1;
  const int br0 = bn * 128 + srow;
  const int br1 = br0 + 64;

  auto stage = [&](int kt, int buf) {
    const unsigned short* As = (kt < 32) ? A1 : A2;
    const int ka = (kt & 31) * 32 + skk;
    const int kw = kt * 32 + skk;
    unsigned short* dA = &lA[buf][wave * 512];  // wave-uniform LDS base
    unsigned short* dB = &lB[buf][wave * 512];
    gld_lds16(As + (size_t)ar0 * 1024 + ka, dA);
    gld_lds16(As + (size_t)ar1 * 1024 + ka, dA + 2048);
    gld_lds16(WT + (size_t)br0 * 2048 + kw, dB);
    gld_lds16(WT + (size_t)br1 * 2048 + kw, dB + 2048);
  };

  stage(0, 0);
  __syncthreads();  // compiler drains vmcnt before s_barrier
  int cur = 0;
#pragma unroll 2
  for (int kt = 0; kt < 64; ++kt) {
    if (kt < 63) stage(kt + 1, cur ^ 1);  // prefetch overlaps compute below
    short8 af[4], bfv[4];
#pragma unroll
    for (int m = 0; m < 4; ++m)
      af[m] = *(const short8*)&lA[cur][(wm * 64 + m * 16 + fr) * 32 + fq * 8];
#pragma unroll
    for (int n = 0; n < 4; ++n)
      bfv[n] = *(const short8*)&lB[cur][(wn * 64 + n * 16 + fr) * 32 + fq * 8];
#pragma unroll
    for (int m = 0; m < 4; ++m)
#pragma unroll
      for (int n = 0; n < 4; ++n)
        acc[m][n] = __builtin_amdgcn_mfma_f32_16x16x32_bf16(af[m], bfv[n], acc[m][n], 0, 0, 0);
    __syncthreads();  // drains vmcnt(0): next buf staged; cur safe to overwrite
    cur ^= 1;
  }

  // epilogue: C/D layout col=lane&15, row=(lane>>4)*4+j  [m89/m91 verified]
#pragma unroll
  for (int m = 0; m < 4; ++m) {
    int r0 = bm * 128 + wm * 64 + m * 16 + fq * 4;
#pragma unroll
    for (int j = 0; j < 4; ++j) {
      int r = r0 + j;
      if (r >= M) continue;
#pragma unroll
      for (int n = 0; n < 4; ++n) {
        int cc = bn * 128 + wn * 64 + n * 16 + fr;
        float v = acc[m][n][j] + bias[cc];
        if (RELU) v = fmaxf(v, 0.f);
        if (OUT_BF16)
          ((unsigned short*)Cout)[(size_t)r * 1024 + cc] = f2bf(v);
        else
          ((float*)Cout)[(size_t)r * 1024 + cc] = v;
      }
    }
  }
}

extern "C" void kernel_launch(void* const* d_in, const int* in_sizes, int n_in,
                              void* d_out, int out_size, void* d_ws, size_t ws_size,
                              hipStream_t stream) {
  const float* x = (const float*)d_in[0];
  const int* esrc = (const int*)d_in[1];
  const int* edst = (const int*)d_in[2];
  const float* Ws0 = (const float*)d_in[3];
  const float* Wn0 = (const float*)d_in[4];
  const float* b0 = (const float*)d_in[5];
  const float* Ws1 = (const float*)d_in[6];
  const float* Wn1 = (const float*)d_in[7];
  const float* b1 = (const float*)d_in[8];
  float* out = (float*)d_out;

  char* ws = (char*)d_ws;
  size_t off = 0;
  auto alloc = [&](size_t bytes) -> void* {
    void* p = ws + off;
    off = (off + bytes + 255) & ~(size_t)255;
    return p;
  };
  unsigned short* x_bf = (unsigned short*)alloc((size_t)NN * DD * 2);
  unsigned short* h_bf = (unsigned short*)alloc((size_t)NN * DD * 2);
  unsigned short* mean_bf = (unsigned short*)alloc((size_t)NN * DD * 2);
  unsigned short* WT0 = (unsigned short*)alloc((size_t)DD * 2048 * 2);
  unsigned short* WT1 = (unsigned short*)alloc((size_t)DD * 2048 * 2);
  int* deg = (int*)alloc((size_t)NN * 4);
  int* rowptr = (int*)alloc((size_t)(NN + 1) * 4);
  int* cursor = (int*)alloc((size_t)NN * 4);
  float* dinv = (float*)alloc((size_t)NN * 4);
  int* srcs = (int*)alloc((size_t)NE * 4);
  int* bsum = (int*)alloc(128 * 4);
  int* boff = (int*)alloc(128 * 4);

  hipMemsetAsync(deg, 0, (size_t)NN * 4, stream);

  k_cast_bf16<<<2048, 256, 0, stream>>>(x, x_bf, NN * DD / 8);
  dim3 tg(16, 16);
  k_transcast<<<tg, 256, 0, stream>>>(Ws0, WT0, 0);
  k_transcast<<<tg, 256, 0, stream>>>(Wn0, WT0, 1024);
  k_transcast<<<tg, 256, 0, stream>>>(Ws1, WT1, 0);
  k_transcast<<<tg, 256, 0, stream>>>(Wn1, WT1, 1024);

  const int nsb = (NN + 255) / 256;  // 98 scan blocks
  k_deg<<<(NE + 255) / 256, 256, 0, stream>>>(edst, deg, NE);
  k_scan1<<<nsb, 256, 0, stream>>>(deg, rowptr, bsum, NN);
  k_scan2<<<1, 128, 0, stream>>>(bsum, boff, rowptr + NN, nsb);
  k_scan3<<<nsb, 256, 0, stream>>>(deg, boff, rowptr, cursor, dinv, NN);
  k_fill<<<(NE + 255) / 256, 256, 0, stream>>>(esrc, edst, cursor, srcs, NE);

  const int nbm = (NN + 127) / 128;  // 196
  dim3 gg(8 * nbm);                  // 1D grid, swizzled in-kernel

  // layer 0
  k_agg<<<(NN + 1) / 2, 256, 0, stream>>>(x_bf, rowptr, srcs, dinv, mean_bf, NN);
  k_gemm<true, true><<<gg, 256, 0, stream>>>(x_bf, mean_bf, WT0, b0, (void*)h_bf, NN);

  // layer 1
  k_agg<<<(NN + 1) / 2, 256, 0, stream>>>(h_bf, rowptr, srcs, dinv, mean_bf, NN);
  k_gemm<false, false><<<gg, 256, 0, stream>>>(h_bf, mean_bf, WT1, b1, (void*)out, NN);
}

// Round 4
// 749.311 us; speedup vs baseline: 1.0784x; 1.0499x over previous
//
#include <hip/hip_runtime.h>
#include <stdint.h>

#define NN 25000
#define NE 400000
#define DD 1024

typedef __attribute__((ext_vector_type(8))) short short8;
typedef __attribute__((ext_vector_type(4))) float f32x4;

__device__ __forceinline__ unsigned short f2bf(float f) {
  union { float f; uint32_t u; } v; v.f = f;
  uint32_t r = v.u + 0x7fffu + ((v.u >> 16) & 1u);
  return (unsigned short)(r >> 16);
}
__device__ __forceinline__ float bf2f(unsigned short h) {
  union { uint32_t u; float f; } v; v.u = ((uint32_t)h) << 16;
  return v.f;
}

__device__ __forceinline__ void gld_lds16(const void* g, void* l) {
  __builtin_amdgcn_global_load_lds(
      (const __attribute__((address_space(1))) void*)g,
      (__attribute__((address_space(3))) void*)l, 16, 0, 0);
}

// ---------------- cast fp32 -> bf16 (vectorized) ----------------
__global__ __launch_bounds__(256) void k_cast_bf16(const float* __restrict__ in,
                                                   unsigned short* __restrict__ out,
                                                   int n8) {
  int i = blockIdx.x * blockDim.x + threadIdx.x;
  int stride = gridDim.x * blockDim.x;
  for (; i < n8; i += stride) {
    const float4* p = (const float4*)(in + (size_t)i * 8);
    float4 a = p[0], b = p[1];
    ushort4 r0, r1;
    r0.x = f2bf(a.x); r0.y = f2bf(a.y); r0.z = f2bf(a.z); r0.w = f2bf(a.w);
    r1.x = f2bf(b.x); r1.y = f2bf(b.y); r1.z = f2bf(b.z); r1.w = f2bf(b.w);
    ushort4* q = (ushort4*)(out + (size_t)i * 8);
    q[0] = r0; q[1] = r1;
  }
}

// ------------- transpose+cast W[k][n] fp32 -> WT[n][2048] bf16 at col kofs -------------
__global__ __launch_bounds__(256) void k_transcast(const float* __restrict__ W,
                                                   unsigned short* __restrict__ WT,
                                                   int kofs) {
  __shared__ unsigned short tile[64][66];
  int t = threadIdx.x;
  int k0 = blockIdx.x * 64, n0 = blockIdx.y * 64;
#pragma unroll
  for (int p = 0; p < 16; ++p) {
    int idx = p * 256 + t;
    int lr = idx >> 6, lc = idx & 63;
    tile[lr][lc] = f2bf(W[(size_t)(k0 + lr) * 1024 + n0 + lc]);
  }
  __syncthreads();
#pragma unroll
  for (int p = 0; p < 16; ++p) {
    int idx = p * 256 + t;
    int lr = idx >> 6, lc = idx & 63;
    WT[(size_t)(n0 + lr) * 2048 + kofs + k0 + lc] = tile[lc][lr];
  }
}

// ---------------- degree ----------------
__global__ __launch_bounds__(256) void k_deg(const int* __restrict__ dst,
                                             int* __restrict__ deg, int E) {
  int i = blockIdx.x * blockDim.x + threadIdx.x;
  if (i < E) atomicAdd(&deg[dst[i]], 1);
}

// ---------------- two-level exclusive scan ----------------
__global__ __launch_bounds__(256) void k_scan1(const int* __restrict__ deg,
                                               int* __restrict__ rowptr,
                                               int* __restrict__ bsum, int N) {
  __shared__ int ws[4];
  int t = threadIdx.x, lane = t & 63, w = t >> 6;
  int i = blockIdx.x * 256 + t;
  int v = (i < N) ? deg[i] : 0;
  int x = v;
#pragma unroll
  for (int off = 1; off < 64; off <<= 1) {
    int y = __shfl_up(x, off);
    if (lane >= off) x += y;
  }
  if (lane == 63) ws[w] = x;
  __syncthreads();
  int wbase = 0;
#pragma unroll
  for (int j = 0; j < 3; ++j)
    if (w > j) wbase += ws[j];
  if (i < N) rowptr[i] = wbase + x - v;
  if (t == 255) bsum[blockIdx.x] = wbase + x;
}

__global__ __launch_bounds__(128) void k_scan2(const int* __restrict__ bsum,
                                               int* __restrict__ boff,
                                               int* __restrict__ rowptr_end, int nb) {
  __shared__ int ws[2];
  int t = threadIdx.x, lane = t & 63, w = t >> 6;
  int v = (t < nb) ? bsum[t] : 0;
  int x = v;
#pragma unroll
  for (int off = 1; off < 64; off <<= 1) {
    int y = __shfl_up(x, off);
    if (lane >= off) x += y;
  }
  if (lane == 63) ws[w] = x;
  __syncthreads();
  int wbase = (w == 1) ? ws[0] : 0;
  if (t < nb) boff[t] = wbase + x - v;
  if (t == 127) *rowptr_end = wbase + x;
}

__global__ __launch_bounds__(256) void k_scan3(const int* __restrict__ deg,
                                               const int* __restrict__ boff,
                                               int* __restrict__ rowptr,
                                               int* __restrict__ cursor,
                                               float* __restrict__ dinv, int N) {
  int i = blockIdx.x * 256 + threadIdx.x;
  if (i < N) {
    int r = rowptr[i] + boff[blockIdx.x];
    rowptr[i] = r;
    cursor[i] = r;
    dinv[i] = 1.0f / fmaxf((float)deg[i], 1.0f);
  }
}

// ---------------- CSR fill (counting sort) ----------------
__global__ __launch_bounds__(256) void k_fill(const int* __restrict__ src,
                                              const int* __restrict__ dst,
                                              int* __restrict__ cursor,
                                              int* __restrict__ srcs, int E) {
  int i = blockIdx.x * blockDim.x + threadIdx.x;
  if (i < E) {
    int p = atomicAdd(&cursor[dst[i]], 1);
    srcs[p] = src[i];
  }
}

// ---------------- mean aggregation: 2 nodes per block, 16B/lane loads ----------------
__global__ __launch_bounds__(256) void k_agg(const unsigned short* __restrict__ h,
                                             const int* __restrict__ rowptr,
                                             const int* __restrict__ srcs,
                                             const float* __restrict__ deg_inv,
                                             unsigned short* __restrict__ mean, int N) {
  int node = blockIdx.x * 2 + (threadIdx.x >> 7);
  if (node >= N) return;
  int t = threadIdx.x & 127;
  int c = t * 8;
  int beg = rowptr[node], end = rowptr[node + 1];
  float a[8];
#pragma unroll
  for (int j = 0; j < 8; ++j) a[j] = 0.f;
  int e = beg;
  for (; e + 1 < end; e += 2) {
    int s0 = srcs[e], s1 = srcs[e + 1];
    short8 v0 = *(const short8*)(h + (size_t)s0 * DD + c);
    short8 v1 = *(const short8*)(h + (size_t)s1 * DD + c);
#pragma unroll
    for (int j = 0; j < 8; ++j)
      a[j] += bf2f((unsigned short)v0[j]) + bf2f((unsigned short)v1[j]);
  }
  if (e < end) {
    int s0 = srcs[e];
    short8 v0 = *(const short8*)(h + (size_t)s0 * DD + c);
#pragma unroll
    for (int j = 0; j < 8; ++j) a[j] += bf2f((unsigned short)v0[j]);
  }
  float di = deg_inv[node];
  short8 r;
#pragma unroll
  for (int j = 0; j < 8; ++j) r[j] = (short)f2bf(a[j] * di);
  *(short8*)(mean + (size_t)node * DD + c) = r;
}

// ============ 256x256 8-phase fused dual-A GEMM (m201 template port) ============
// C = [A1 | A2] @ WT^T + b  where WT[n][2048] bf16 (k<1024 Wself, k>=1024 Wneigh).
// BM=BN=256, BK=64, 512 thr = 8 waves (2M x 4N), per-wave out 128x64.
// LDS 128KB: 2 dbuf x { A-half0 16K | A-half1 16K | B-half0 16K | B-half1 16K }.
// Each 16KB half = 16 subtiles of 1024B (16 rows x 32 bf16 cols), st_16x32 swizzle:
// byte ^= ((byte>>9)&1)<<5 within subtile. gload_lds writes LINEAR; source address
// pre-swizzled; ds_read applies the same XOR (involution, rule #21).
// K-tile = 4 phases {ds_read 12xb128 ; stage ; s_barrier ; setprio1 16xMFMA setprio0 ;
// s_barrier}. Staging for tile t+1 issued at phases 0-2; single vmcnt(0) drain at
// tile end (counted-vmcnt discipline: never drain mid-tile).
template <bool RELU, bool OUT_BF16>
__global__ __launch_bounds__(512, 2) void k_gemm(const unsigned short* __restrict__ A1,
                                                 const unsigned short* __restrict__ A2,
                                                 const unsigned short* __restrict__ WT,
                                                 const float* __restrict__ bias,
                                                 void* __restrict__ Cout, int M) {
  __shared__ __align__(16) char ldsc[131072];  // 128 KB
  const int t = threadIdx.x;
  const int lane = t & 63, wave = t >> 6;
  const int wm = wave >> 2, wn = wave & 3;  // 2M x 4N wave grid
  const int fr = lane & 15, fq = lane >> 4;

  // XCD swizzle (bijective: 392 % 8 == 0, cpx = 49), bn-fastest within chunk
  const int cpx = gridDim.x >> 3;
  const int g = (blockIdx.x & 7) * cpx + (blockIdx.x >> 3);
  const int bm = g >> 2, bn = g & 3;  // 98 x 4 tiles

  // staging source swizzle (per-lane): lane covers swizzled subtile bytes
  int sb = lane * 16;
  sb ^= ((sb >> 9) & 1) << 5;
  const int s_r = sb >> 6;         // row within 16-row subtile
  const int s_k = (sb & 63) >> 1;  // k element within 32-col subtile

  // ds_read swizzled offset within subtile
  int rd = fr * 64 + fq * 16;
  rd ^= ((rd >> 9) & 1) << 5;

  f32x4 acc[8][4];
#pragma unroll
  for (int m = 0; m < 8; ++m)
#pragma unroll
    for (int n = 0; n < 4; ++n) acc[m][n] = (f32x4){0.f, 0.f, 0.f, 0.f};

  // hi: 0,1 = A halves (rows bm*256 + half*128); 2,3 = B halves (rows bn*256 + half*128)
  auto stage_half = [&](int t1, int hi, int bufb) {
    const bool isA = hi < 2;
    const int half = hi & 1;
    const unsigned short* src;
    int stride, kb, row0;
    if (isA) {
      src = (t1 < 16) ? A1 : A2;
      stride = 1024;
      kb = (t1 & 15) * 64;
      row0 = bm * 256 + half * 128;
    } else {
      src = WT;
      stride = 2048;
      kb = t1 * 64;
      row0 = bn * 256 + half * 128;
    }
    char* lbase = ldsc + bufb + hi * 16384 + wave * 1024;  // wave-uniform dest
#pragma unroll
    for (int j = 0; j < 2; ++j) {
      int sub = j * 8 + wave;
      int msub = sub >> 1, ksub = sub & 1;
      int row = row0 + msub * 16 + s_r;
      if (isA && row > M - 1) row = M - 1;  // tail clamp (stores guarded)
      gld_lds16(src + (size_t)row * stride + kb + ksub * 32 + s_k, lbase + j * 8192);
    }
  };

// one phase: quadrant (QM,QN); 8 A-reads + 4 B-reads, 16 MFMA
#define PHASE(QM, QN, STAGE)                                                          \
  {                                                                                   \
    short8 av[4][2], bv[2][2];                                                        \
    _Pragma("unroll") for (int im = 0; im < 4; ++im)                                  \
        _Pragma("unroll") for (int ks = 0; ks < 2; ++ks)                              \
            av[im][ks] = *(const short8*)(pa + (((QM) * 4 + im) * 2 + ks) * 1024);    \
    _Pragma("unroll") for (int in = 0; in < 2; ++in)                                  \
        _Pragma("unroll") for (int ks = 0; ks < 2; ++ks)                              \
            bv[in][ks] = *(const short8*)(pb + (((QN) * 2 + in) * 2 + ks) * 1024);    \
    STAGE;                                                                            \
    __builtin_amdgcn_s_barrier();                                                     \
    __builtin_amdgcn_s_setprio(1);                                                    \
    _Pragma("unroll") for (int im = 0; im < 4; ++im)                                  \
        _Pragma("unroll") for (int in = 0; in < 2; ++in)                              \
            _Pragma("unroll") for (int ks = 0; ks < 2; ++ks)                          \
                acc[(QM) * 4 + im][(QN) * 2 + in] =                                   \
                    __builtin_amdgcn_mfma_f32_16x16x32_bf16(                          \
                        av[im][ks], bv[in][ks], acc[(QM) * 4 + im][(QN) * 2 + in],    \
                        0, 0, 0);                                                     \
    __builtin_amdgcn_s_setprio(0);                                                    \
  }

  // prologue: stage K-tile 0 into buf 0, drain, barrier
  stage_half(0, 0, 0);
  stage_half(0, 1, 0);
  stage_half(0, 2, 0);
  stage_half(0, 3, 0);
  asm volatile("s_waitcnt vmcnt(0)" ::: "memory");
  __builtin_amdgcn_s_barrier();

#pragma unroll 1
  for (int kt = 0; kt < 32; ++kt) {
    const int cbuf = (kt & 1) << 16;
    const int nbuf = cbuf ^ 65536;
    const bool pf = kt < 31;
    // per-wave read bases in current buffer (swizzled offset folded in)
    const char* pa = ldsc + cbuf + wm * 16384 + rd;                              // A half wm
    const char* pb = ldsc + cbuf + 32768 + (wn >> 1) * 16384 + (wn & 1) * 8192 + rd;  // B

    PHASE(0, 0, if (pf) { stage_half(kt + 1, 0, nbuf); stage_half(kt + 1, 1, nbuf); })
    __builtin_amdgcn_s_barrier();
    PHASE(0, 1, if (pf) stage_half(kt + 1, 2, nbuf);)
    __builtin_amdgcn_s_barrier();
    PHASE(1, 0, if (pf) stage_half(kt + 1, 3, nbuf);)
    __builtin_amdgcn_s_barrier();
    PHASE(1, 1, ;)
    asm volatile("s_waitcnt vmcnt(0)" ::: "memory");  // tile t+1 halves landed
    __builtin_amdgcn_s_barrier();
  }
#undef PHASE

  // epilogue: C/D layout col=lane&15, row=(lane>>4)*4+j  [m89/m91 verified]
#pragma unroll
  for (int mf = 0; mf < 8; ++mf) {
    int r0 = bm * 256 + wm * 128 + mf * 16 + fq * 4;
#pragma unroll
    for (int j = 0; j < 4; ++j) {
      int r = r0 + j;
      if (r >= M) continue;
#pragma unroll
      for (int nf = 0; nf < 4; ++nf) {
        int c = bn * 256 + wn * 64 + nf * 16 + fr;
        float v = acc[mf][nf][j] + bias[c];
        if (RELU) v = fmaxf(v, 0.f);
        if (OUT_BF16)
          ((unsigned short*)Cout)[(size_t)r * 1024 + c] = f2bf(v);
        else
          ((float*)Cout)[(size_t)r * 1024 + c] = v;
      }
    }
  }
}

extern "C" void kernel_launch(void* const* d_in, const int* in_sizes, int n_in,
                              void* d_out, int out_size, void* d_ws, size_t ws_size,
                              hipStream_t stream) {
  const float* x = (const float*)d_in[0];
  const int* esrc = (const int*)d_in[1];
  const int* edst = (const int*)d_in[2];
  const float* Ws0 = (const float*)d_in[3];
  const float* Wn0 = (const float*)d_in[4];
  const float* b0 = (const float*)d_in[5];
  const float* Ws1 = (const float*)d_in[6];
  const float* Wn1 = (const float*)d_in[7];
  const float* b1 = (const float*)d_in[8];
  float* out = (float*)d_out;

  char* ws = (char*)d_ws;
  size_t off = 0;
  auto alloc = [&](size_t bytes) -> void* {
    void* p = ws + off;
    off = (off + bytes + 255) & ~(size_t)255;
    return p;
  };
  unsigned short* x_bf = (unsigned short*)alloc((size_t)NN * DD * 2);
  unsigned short* h_bf = (unsigned short*)alloc((size_t)NN * DD * 2);
  unsigned short* mean_bf = (unsigned short*)alloc((size_t)NN * DD * 2);
  unsigned short* WT0 = (unsigned short*)alloc((size_t)DD * 2048 * 2);
  unsigned short* WT1 = (unsigned short*)alloc((size_t)DD * 2048 * 2);
  int* deg = (int*)alloc((size_t)NN * 4);
  int* rowptr = (int*)alloc((size_t)(NN + 1) * 4);
  int* cursor = (int*)alloc((size_t)NN * 4);
  float* dinv = (float*)alloc((size_t)NN * 4);
  int* srcs = (int*)alloc((size_t)NE * 4);
  int* bsum = (int*)alloc(128 * 4);
  int* boff = (int*)alloc(128 * 4);

  hipMemsetAsync(deg, 0, (size_t)NN * 4, stream);

  k_cast_bf16<<<2048, 256, 0, stream>>>(x, x_bf, NN * DD / 8);
  dim3 tg(16, 16);
  k_transcast<<<tg, 256, 0, stream>>>(Ws0, WT0, 0);
  k_transcast<<<tg, 256, 0, stream>>>(Wn0, WT0, 1024);
  k_transcast<<<tg, 256, 0, stream>>>(Ws1, WT1, 0);
  k_transcast<<<tg, 256, 0, stream>>>(Wn1, WT1, 1024);

  const int nsb = (NN + 255) / 256;
  k_deg<<<(NE + 255) / 256, 256, 0, stream>>>(edst, deg, NE);
  k_scan1<<<nsb, 256, 0, stream>>>(deg, rowptr, bsum, NN);
  k_scan2<<<1, 128, 0, stream>>>(bsum, boff, rowptr + NN, nsb);
  k_scan3<<<nsb, 256, 0, stream>>>(deg, boff, rowptr, cursor, dinv, NN);
  k_fill<<<(NE + 255) / 256, 256, 0, stream>>>(esrc, edst, cursor, srcs, NE);

  const int nbm = (NN + 255) / 256;  // 98 M-tiles of 256
  dim3 gg(nbm * 4);                  // x 4 N-tiles = 392 blocks (392 % 8 == 0)

  // layer 0
  k_agg<<<(NN + 1) / 2, 256, 0, stream>>>(x_bf, rowptr, srcs, dinv, mean_bf, NN);
  k_gemm<true, true><<<gg, 512, 0, stream>>>(x_bf, mean_bf, WT0, b0, (void*)h_bf, NN);

  // layer 1
  k_agg<<<(NN + 1) / 2, 256, 0, stream>>>(h_bf, rowptr, srcs, dinv, mean_bf, NN);
  k_gemm<false, false><<<gg, 512, 0, stream>>>(h_bf, mean_bf, WT1, b1, (void*)out, NN);
}

// Round 5
// 740.163 us; speedup vs baseline: 1.0918x; 1.0124x over previous
//
#include <hip/hip_runtime.h>
#include <stdint.h>

#define NN 25000
#define NE 400000
#define DD 1024

typedef __attribute__((ext_vector_type(8))) short short8;
typedef __attribute__((ext_vector_type(4))) float f32x4;

__device__ __forceinline__ unsigned short f2bf(float f) {
  union { float f; uint32_t u; } v; v.f = f;
  uint32_t r = v.u + 0x7fffu + ((v.u >> 16) & 1u);
  return (unsigned short)(r >> 16);
}
__device__ __forceinline__ float bf2f(unsigned short h) {
  union { uint32_t u; float f; } v; v.u = ((uint32_t)h) << 16;
  return v.f;
}

__device__ __forceinline__ void gld_lds16(const void* g, void* l) {
  __builtin_amdgcn_global_load_lds(
      (const __attribute__((address_space(1))) void*)g,
      (__attribute__((address_space(3))) void*)l, 16, 0, 0);
}

// ---------------- cast fp32 -> bf16 (vectorized) ----------------
__global__ __launch_bounds__(256) void k_cast_bf16(const float* __restrict__ in,
                                                   unsigned short* __restrict__ out,
                                                   int n8) {
  int i = blockIdx.x * blockDim.x + threadIdx.x;
  int stride = gridDim.x * blockDim.x;
  for (; i < n8; i += stride) {
    const float4* p = (const float4*)(in + (size_t)i * 8);
    float4 a = p[0], b = p[1];
    ushort4 r0, r1;
    r0.x = f2bf(a.x); r0.y = f2bf(a.y); r0.z = f2bf(a.z); r0.w = f2bf(a.w);
    r1.x = f2bf(b.x); r1.y = f2bf(b.y); r1.z = f2bf(b.z); r1.w = f2bf(b.w);
    ushort4* q = (ushort4*)(out + (size_t)i * 8);
    q[0] = r0; q[1] = r1;
  }
}

// ------------- transpose+cast W[k][n] fp32 -> WT[n][2048] bf16 at col kofs -------------
__global__ __launch_bounds__(256) void k_transcast(const float* __restrict__ W,
                                                   unsigned short* __restrict__ WT,
                                                   int kofs) {
  __shared__ unsigned short tile[64][66];
  int t = threadIdx.x;
  int k0 = blockIdx.x * 64, n0 = blockIdx.y * 64;
#pragma unroll
  for (int p = 0; p < 16; ++p) {
    int idx = p * 256 + t;
    int lr = idx >> 6, lc = idx & 63;
    tile[lr][lc] = f2bf(W[(size_t)(k0 + lr) * 1024 + n0 + lc]);
  }
  __syncthreads();
#pragma unroll
  for (int p = 0; p < 16; ++p) {
    int idx = p * 256 + t;
    int lr = idx >> 6, lc = idx & 63;
    WT[(size_t)(n0 + lr) * 2048 + kofs + k0 + lc] = tile[lc][lr];
  }
}

// ---------------- degree ----------------
__global__ __launch_bounds__(256) void k_deg(const int* __restrict__ dst,
                                             int* __restrict__ deg, int E) {
  int i = blockIdx.x * blockDim.x + threadIdx.x;
  if (i < E) atomicAdd(&deg[dst[i]], 1);
}

// ---------------- two-level exclusive scan ----------------
__global__ __launch_bounds__(256) void k_scan1(const int* __restrict__ deg,
                                               int* __restrict__ rowptr,
                                               int* __restrict__ bsum, int N) {
  __shared__ int ws[4];
  int t = threadIdx.x, lane = t & 63, w = t >> 6;
  int i = blockIdx.x * 256 + t;
  int v = (i < N) ? deg[i] : 0;
  int x = v;
#pragma unroll
  for (int off = 1; off < 64; off <<= 1) {
    int y = __shfl_up(x, off);
    if (lane >= off) x += y;
  }
  if (lane == 63) ws[w] = x;
  __syncthreads();
  int wbase = 0;
#pragma unroll
  for (int j = 0; j < 3; ++j)
    if (w > j) wbase += ws[j];
  if (i < N) rowptr[i] = wbase + x - v;
  if (t == 255) bsum[blockIdx.x] = wbase + x;
}

__global__ __launch_bounds__(128) void k_scan2(const int* __restrict__ bsum,
                                               int* __restrict__ boff,
                                               int* __restrict__ rowptr_end, int nb) {
  __shared__ int ws[2];
  int t = threadIdx.x, lane = t & 63, w = t >> 6;
  int v = (t < nb) ? bsum[t] : 0;
  int x = v;
#pragma unroll
  for (int off = 1; off < 64; off <<= 1) {
    int y = __shfl_up(x, off);
    if (lane >= off) x += y;
  }
  if (lane == 63) ws[w] = x;
  __syncthreads();
  int wbase = (w == 1) ? ws[0] : 0;
  if (t < nb) boff[t] = wbase + x - v;
  if (t == 127) *rowptr_end = wbase + x;
}

__global__ __launch_bounds__(256) void k_scan3(const int* __restrict__ deg,
                                               const int* __restrict__ boff,
                                               int* __restrict__ rowptr,
                                               int* __restrict__ cursor,
                                               float* __restrict__ dinv, int N) {
  int i = blockIdx.x * 256 + threadIdx.x;
  if (i < N) {
    int r = rowptr[i] + boff[blockIdx.x];
    rowptr[i] = r;
    cursor[i] = r;
    dinv[i] = 1.0f / fmaxf((float)deg[i], 1.0f);
  }
}

// ---------------- CSR fill (counting sort) ----------------
__global__ __launch_bounds__(256) void k_fill(const int* __restrict__ src,
                                              const int* __restrict__ dst,
                                              int* __restrict__ cursor,
                                              int* __restrict__ srcs, int E) {
  int i = blockIdx.x * blockDim.x + threadIdx.x;
  if (i < E) {
    int p = atomicAdd(&cursor[dst[i]], 1);
    srcs[p] = src[i];
  }
}

// ---------------- mean aggregation: 2 nodes per block, 16B/lane, 4-deep ILP --------
__global__ __launch_bounds__(256) void k_agg(const unsigned short* __restrict__ h,
                                             const int* __restrict__ rowptr,
                                             const int* __restrict__ srcs,
                                             const float* __restrict__ deg_inv,
                                             unsigned short* __restrict__ mean, int N) {
  int node = blockIdx.x * 2 + (threadIdx.x >> 7);
  if (node >= N) return;
  int t = threadIdx.x & 127;
  int c = t * 8;
  int beg = rowptr[node], end = rowptr[node + 1];
  float a[8];
#pragma unroll
  for (int j = 0; j < 8; ++j) a[j] = 0.f;
  int e = beg;
  for (; e + 3 < end; e += 4) {
    int s0 = srcs[e], s1 = srcs[e + 1], s2 = srcs[e + 2], s3 = srcs[e + 3];
    short8 v0 = *(const short8*)(h + (size_t)s0 * DD + c);
    short8 v1 = *(const short8*)(h + (size_t)s1 * DD + c);
    short8 v2 = *(const short8*)(h + (size_t)s2 * DD + c);
    short8 v3 = *(const short8*)(h + (size_t)s3 * DD + c);
#pragma unroll
    for (int j = 0; j < 8; ++j)
      a[j] += (bf2f((unsigned short)v0[j]) + bf2f((unsigned short)v1[j])) +
              (bf2f((unsigned short)v2[j]) + bf2f((unsigned short)v3[j]));
  }
  for (; e < end; ++e) {
    int s0 = srcs[e];
    short8 v0 = *(const short8*)(h + (size_t)s0 * DD + c);
#pragma unroll
    for (int j = 0; j < 8; ++j) a[j] += bf2f((unsigned short)v0[j]);
  }
  float di = deg_inv[node];
  short8 r;
#pragma unroll
  for (int j = 0; j < 8; ++j) r[j] = (short)f2bf(a[j] * di);
  *(short8*)(mean + (size_t)node * DD + c) = r;
}

// ========= 256x256 fused dual-A GEMM, 4-deep LDS pipeline, counted vmcnt =========
// C = [A1 | A2] @ WT^T + b.  WT[n][2048] bf16 (k<1024 Wself, k>=1024 Wneigh).
// BM=BN=256, BK=32, 512 thr = 8 waves (2M x 4N), per-wave out 128x64.
// LDS 128KB = 4 circular buffers x 32KB { A 16K | B 16K }, each region = 16
// subtiles of 1024B (16 rows x 32 bf16), st_16x32 swizzle byte^=((byte>>9)&1)<<5.
// Pipeline: prologue stages tiles 0-2; tile t stages tile t+3 into buf (t+3)&3
// (= (t-1)&3, safe: its reads completed before tile t's start barrier).
// 4 gld_lds/thread/tile (A0,A1,B0,B1 halves, FIFO). Tile-start wait:
// vmcnt(8) = 2 younger tiles in flight, own tile landed. NEVER drains to 0
// mid-loop (T4 counted-vmcnt: +38% vs drain0, m218).
template <bool RELU, bool OUT_BF16>
__global__ __launch_bounds__(512, 2) void k_gemm(const unsigned short* __restrict__ A1,
                                                 const unsigned short* __restrict__ A2,
                                                 const unsigned short* __restrict__ WT,
                                                 const float* __restrict__ bias,
                                                 void* __restrict__ Cout, int M) {
  __shared__ __align__(16) char ldsc[131072];  // 4 x 32KB
  const int t = threadIdx.x;
  const int lane = t & 63, wave = t >> 6;
  const int wm = wave >> 2, wn = wave & 3;  // 2M x 4N wave grid
  const int fr = lane & 15, fq = lane >> 4;

  // XCD swizzle (bijective: 392 % 8 == 0), bn-fastest within chunk
  const int cpx = gridDim.x >> 3;
  const int g = (blockIdx.x & 7) * cpx + (blockIdx.x >> 3);
  const int bm = g >> 2, bn = g & 3;  // 98 x 4 tiles

  // staging source swizzle: lane covers LINEAR subtile bytes [lane*16,+16);
  // source fetched from swizzled position (involution with read-side XOR)
  int sb = lane * 16;
  sb ^= ((sb >> 9) & 1) << 5;
  const int s_r = sb >> 6;         // row within 16-row subtile
  const int s_k = (sb & 63) >> 1;  // k element within 32-col subtile

  // ds_read swizzled offset within subtile
  int rd = fr * 64 + fq * 16;
  rd ^= ((rd >> 9) & 1) << 5;

  f32x4 acc[8][4];
#pragma unroll
  for (int m = 0; m < 8; ++m)
#pragma unroll
    for (int n = 0; n < 4; ++n) acc[m][n] = (f32x4){0.f, 0.f, 0.f, 0.f};

  // which: 0,1 = A halves (block rows 0-127 / 128-255); 2,3 = B halves.
  // One gld per thread: wave stages its 1024B subtile (wave-uniform dest).
  auto stage_half = [&](int t1, int which) {
    char* buf = ldsc + ((t1 & 3) << 15);
    const int half = which & 1;
    const unsigned short* src;
    int stride, kb, row0;
    if (which < 2) {
      src = (t1 < 32) ? A1 : A2;
      stride = 1024;
      kb = (t1 & 31) * 32;
      row0 = bm * 256 + half * 128;
    } else {
      src = WT;
      stride = 2048;
      kb = t1 * 32;
      row0 = bn * 256 + half * 128;
    }
    int row = row0 + wave * 16 + s_r;
    if (which < 2 && row > M - 1) row = M - 1;  // tail clamp (stores guarded)
    char* dst = buf + (which >> 1) * 16384 + half * 8192 + wave * 1024;
    gld_lds16(src + (size_t)row * stride + kb + s_k, dst);
  };

// phase QM: 8 ds_read_b128, stage, barrier, 16 MFMA
#define PHASE(QM, STAGE)                                                           \
  {                                                                                \
    short8 av[4], bv[4];                                                           \
    _Pragma("unroll") for (int im = 0; im < 4; ++im)                               \
        av[im] = *(const short8*)(pa + ((QM) * 4 + im) * 1024);                    \
    _Pragma("unroll") for (int nf = 0; nf < 4; ++nf)                               \
        bv[nf] = *(const short8*)(pb + nf * 1024);                                 \
    STAGE;                                                                         \
    __builtin_amdgcn_s_barrier();                                                  \
    __builtin_amdgcn_s_setprio(1);                                                 \
    _Pragma("unroll") for (int im = 0; im < 4; ++im)                               \
        _Pragma("unroll") for (int nf = 0; nf < 4; ++nf)                           \
            acc[(QM) * 4 + im][nf] = __builtin_amdgcn_mfma_f32_16x16x32_bf16(      \
                av[im], bv[nf], acc[(QM) * 4 + im][nf], 0, 0, 0);                  \
    __builtin_amdgcn_s_setprio(0);                                                 \
  }

  // prologue: stage tiles 0,1,2 (12 gld/thread, FIFO order)
#pragma unroll
  for (int pt = 0; pt < 3; ++pt) {
    stage_half(pt, 0); stage_half(pt, 1); stage_half(pt, 2); stage_half(pt, 3);
  }

#pragma unroll 1
  for (int kt = 0; kt < 64; ++kt) {
    // own tile's 4 loads landed; up to 2 younger tiles (8 loads) stay in flight
    if (kt < 62)
      asm volatile("s_waitcnt vmcnt(8)" ::: "memory");
    else if (kt == 62)
      asm volatile("s_waitcnt vmcnt(4)" ::: "memory");
    else
      asm volatile("s_waitcnt vmcnt(0)" ::: "memory");
    __builtin_amdgcn_sched_barrier(0);
    __builtin_amdgcn_s_barrier();  // all waves' loads for this tile landed

    const char* pa = ldsc + ((kt & 3) << 15) + wm * 8192 + rd;
    const char* pb = ldsc + ((kt & 3) << 15) + 16384 + wn * 4096 + rd;
    const bool pf = kt < 61;

    PHASE(0, if (pf) { stage_half(kt + 3, 0); stage_half(kt + 3, 1); })
    __builtin_amdgcn_s_barrier();
    PHASE(1, if (pf) { stage_half(kt + 3, 2); stage_half(kt + 3, 3); })
  }
#undef PHASE

  // epilogue: C/D layout col=lane&15, row=(lane>>4)*4+j  [m89/m91 verified]
#pragma unroll
  for (int mf = 0; mf < 8; ++mf) {
    int r0 = bm * 256 + wm * 128 + mf * 16 + fq * 4;
#pragma unroll
    for (int j = 0; j < 4; ++j) {
      int r = r0 + j;
      if (r >= M) continue;
#pragma unroll
      for (int nf = 0; nf < 4; ++nf) {
        int c = bn * 256 + wn * 64 + nf * 16 + fr;
        float v = acc[mf][nf][j] + bias[c];
        if (RELU) v = fmaxf(v, 0.f);
        if (OUT_BF16)
          ((unsigned short*)Cout)[(size_t)r * 1024 + c] = f2bf(v);
        else
          ((float*)Cout)[(size_t)r * 1024 + c] = v;
      }
    }
  }
}

extern "C" void kernel_launch(void* const* d_in, const int* in_sizes, int n_in,
                              void* d_out, int out_size, void* d_ws, size_t ws_size,
                              hipStream_t stream) {
  const float* x = (const float*)d_in[0];
  const int* esrc = (const int*)d_in[1];
  const int* edst = (const int*)d_in[2];
  const float* Ws0 = (const float*)d_in[3];
  const float* Wn0 = (const float*)d_in[4];
  const float* b0 = (const float*)d_in[5];
  const float* Ws1 = (const float*)d_in[6];
  const float* Wn1 = (const float*)d_in[7];
  const float* b1 = (const float*)d_in[8];
  float* out = (float*)d_out;

  char* ws = (char*)d_ws;
  size_t off = 0;
  auto alloc = [&](size_t bytes) -> void* {
    void* p = ws + off;
    off = (off + bytes + 255) & ~(size_t)255;
    return p;
  };
  unsigned short* x_bf = (unsigned short*)alloc((size_t)NN * DD * 2);
  unsigned short* h_bf = (unsigned short*)alloc((size_t)NN * DD * 2);
  unsigned short* mean_bf = (unsigned short*)alloc((size_t)NN * DD * 2);
  unsigned short* WT0 = (unsigned short*)alloc((size_t)DD * 2048 * 2);
  unsigned short* WT1 = (unsigned short*)alloc((size_t)DD * 2048 * 2);
  int* deg = (int*)alloc((size_t)NN * 4);
  int* rowptr = (int*)alloc((size_t)(NN + 1) * 4);
  int* cursor = (int*)alloc((size_t)NN * 4);
  float* dinv = (float*)alloc((size_t)NN * 4);
  int* srcs = (int*)alloc((size_t)NE * 4);
  int* bsum = (int*)alloc(128 * 4);
  int* boff = (int*)alloc(128 * 4);

  hipMemsetAsync(deg, 0, (size_t)NN * 4, stream);

  k_cast_bf16<<<2048, 256, 0, stream>>>(x, x_bf, NN * DD / 8);
  dim3 tg(16, 16);
  k_transcast<<<tg, 256, 0, stream>>>(Ws0, WT0, 0);
  k_transcast<<<tg, 256, 0, stream>>>(Wn0, WT0, 1024);
  k_transcast<<<tg, 256, 0, stream>>>(Ws1, WT1, 0);
  k_transcast<<<tg, 256, 0, stream>>>(Wn1, WT1, 1024);

  const int nsb = (NN + 255) / 256;
  k_deg<<<(NE + 255) / 256, 256, 0, stream>>>(edst, deg, NE);
  k_scan1<<<nsb, 256, 0, stream>>>(deg, rowptr, bsum, NN);
  k_scan2<<<1, 128, 0, stream>>>(bsum, boff, rowptr + NN, nsb);
  k_scan3<<<nsb, 256, 0, stream>>>(deg, boff, rowptr, cursor, dinv, NN);
  k_fill<<<(NE + 255) / 256, 256, 0, stream>>>(esrc, edst, cursor, srcs, NE);

  const int nbm = (NN + 255) / 256;  // 98 M-tiles of 256
  dim3 gg(nbm * 4);                  // x 4 N-tiles = 392 blocks (392 % 8 == 0)

  // layer 0
  k_agg<<<(NN + 1) / 2, 256, 0, stream>>>(x_bf, rowptr, srcs, dinv, mean_bf, NN);
  k_gemm<true, true><<<gg, 512, 0, stream>>>(x_bf, mean_bf, WT0, b0, (void*)h_bf, NN);

  // layer 1
  k_agg<<<(NN + 1) / 2, 256, 0, stream>>>(h_bf, rowptr, srcs, dinv, mean_bf, NN);
  k_gemm<false, false><<<gg, 512, 0, stream>>>(h_bf, mean_bf, WT1, b1, (void*)out, NN);
}